// Round 1
// baseline (1195.773 us; speedup 1.0000x reference)
//
#include <hip/hip_runtime.h>
#include <hip/hip_bf16.h>

// Problem constants (fixed by the reference)
#define BB 4
#define TT 1024
#define DD 1024
#define HH 16
#define HDIM 64
#define MM (BB*TT)          // 4096
#define SCALE 0.125f        // 1/sqrt(64)

// ---------------------------------------------------------------------------
// Tiled fp32 GEMM: C[m][n] = sum_k A[m][k] * W[n][k] + bias[n]
// A: MxK row-major, W: NxK row-major (so this computes A @ W^T + bias).
// 128x128 tile, 256 threads, 8x8 micro-tile per thread, BK=8.
// MODE 0: scatter to q/k buffers  (N=2048; n -> c,h,d)
// MODE 1: scatter to pk buffer    (N=1024; n -> h,d)
// MODE 2: plain row-major store   (N=1024)
// ---------------------------------------------------------------------------
template<int MODE>
__global__ __launch_bounds__(256)
void gemm_f32(const float* __restrict__ A, const float* __restrict__ W,
              const float* __restrict__ bias,
              float* __restrict__ dst0, float* __restrict__ dst1,
              int M, int N, int K)
{
    __shared__ float As[8][132];   // [k][m], padded (132%32=4 -> <=2-way), 132*4B%16==0 -> float4-aligned
    __shared__ float Bs[8][132];   // [k][n]

    const int tid = threadIdx.x;
    const int m0 = blockIdx.y * 128;
    const int n0 = blockIdx.x * 128;
    const int tx = tid & 15;       // col group
    const int ty = tid >> 4;       // row group

    float acc[8][8];
#pragma unroll
    for (int i = 0; i < 8; ++i)
#pragma unroll
        for (int j = 0; j < 8; ++j) acc[i][j] = 0.f;

    const int lr = tid >> 1;          // 0..127 (row within tile)
    const int lk = (tid & 1) * 4;     // 0 or 4 (k within tile)

    for (int k0 = 0; k0 < K; k0 += 8) {
        const float4 av = *(const float4*)&A[(size_t)(m0 + lr) * K + k0 + lk];
        const float4 bv = *(const float4*)&W[(size_t)(n0 + lr) * K + k0 + lk];
        __syncthreads();   // protect previous iteration's LDS reads
        As[lk + 0][lr] = av.x; As[lk + 1][lr] = av.y; As[lk + 2][lr] = av.z; As[lk + 3][lr] = av.w;
        Bs[lk + 0][lr] = bv.x; Bs[lk + 1][lr] = bv.y; Bs[lk + 2][lr] = bv.z; Bs[lk + 3][lr] = bv.w;
        __syncthreads();
#pragma unroll
        for (int k = 0; k < 8; ++k) {
            const float4 a0 = *(const float4*)&As[k][ty * 4];
            const float4 a1 = *(const float4*)&As[k][ty * 4 + 64];
            const float4 b0 = *(const float4*)&Bs[k][tx * 4];
            const float4 b1 = *(const float4*)&Bs[k][tx * 4 + 64];
            const float a[8] = {a0.x, a0.y, a0.z, a0.w, a1.x, a1.y, a1.z, a1.w};
            const float b[8] = {b0.x, b0.y, b0.z, b0.w, b1.x, b1.y, b1.z, b1.w};
#pragma unroll
            for (int i = 0; i < 8; ++i)
#pragma unroll
                for (int j = 0; j < 8; ++j)
                    acc[i][j] = fmaf(a[i], b[j], acc[i][j]);
        }
    }

#pragma unroll
    for (int i = 0; i < 8; ++i) {
        const int m = m0 + ty * 4 + (i & 3) + ((i >= 4) ? 64 : 0);
#pragma unroll
        for (int j = 0; j < 8; ++j) {
            const int n = n0 + tx * 4 + (j & 3) + ((j >= 4) ? 64 : 0);
            const float v = acc[i][j] + bias[n];
            if (MODE == 0) {
                // n in [0,2048): c = n>>10 selects q/k, h = (n&1023)>>6, d = n&63
                const int b = m >> 10, t = m & 1023;
                const int c = n >> 10, h = (n & 1023) >> 6, d = n & 63;
                float* dst = c ? dst1 : dst0;
                dst[((((size_t)b * HH + h) << 10) + t) * HDIM + d] = v;
            } else if (MODE == 1) {
                const int b = m >> 10, t = m & 1023;
                const int h = n >> 6, d = n & 63;
                dst0[((((size_t)b * HH + h) << 10) + t) * HDIM + d] = v;
            } else {
                dst0[(size_t)m * N + n] = v;
            }
        }
    }
}

// kp += k  (elementwise over B*H*T*HD = 4M floats)
__global__ __launch_bounds__(256)
void add_kp_kernel(float* __restrict__ kp, const float* __restrict__ k)
{
    const size_t i = ((size_t)blockIdx.x * 256 + threadIdx.x) * 4;
    float4 a = *(const float4*)&kp[i];
    const float4 b = *(const float4*)&k[i];
    a.x += b.x; a.y += b.y; a.z += b.z; a.w += b.w;
    *(float4*)&kp[i] = a;
}

// ---------------------------------------------------------------------------
// Fused attention: per block = 8 q-rows of one (b,h).
// Phase 1: S[8][1024] = q @ kp^T * scale   (kp staged 32 rows at a time in LDS)
// Phase 2: softmax rows (32 lanes per row), normalize, write attn output
// Phase 3: ctx = S @ k                      (k staged 32 rows at a time)
// ---------------------------------------------------------------------------
__global__ __launch_bounds__(256)
void attn_kernel(const float* __restrict__ q,    // [B][H][T][64]
                 const float* __restrict__ kmat, // [B][H][T][64]
                 const float* __restrict__ kp,   // [B][H][T][64]
                 float* __restrict__ attn,       // [B][H][T][T]
                 float* __restrict__ ctx)        // [B][T][H][64]
{
    __shared__ float S[8][1028];
    __shared__ float kt[32][68];
    __shared__ float qs[8][68];
    __shared__ float rinv[8];

    const int tid = threadIdx.x;
    const int q0 = blockIdx.x * 8;
    const int h  = blockIdx.y;
    const int b  = blockIdx.z;
    const size_t headbase = ((size_t)(b * HH + h)) << 16;   // *T*HDIM

    // load q tile (8x64) into LDS, then into registers
    {
        const int r = tid >> 5, c2 = (tid & 31) * 2;
        const float2 v = *(const float2*)&q[headbase + (size_t)(q0 + r) * HDIM + c2];
        qs[r][c2] = v.x; qs[r][c2 + 1] = v.y;
    }
    __syncthreads();

    const int qi = tid >> 5;     // 0..7  (row for phase 1/2)
    const int kj = tid & 31;     // 0..31 (col within k-tile)
    float qreg[64];
#pragma unroll
    for (int d = 0; d < 64; d += 4) {
        const float4 v = *(const float4*)&qs[qi][d];
        qreg[d] = v.x; qreg[d + 1] = v.y; qreg[d + 2] = v.z; qreg[d + 3] = v.w;
    }

    // ---- phase 1: scores ----
    for (int kt0 = 0; kt0 < TT; kt0 += 32) {
        __syncthreads();   // protect previous tile's reads
#pragma unroll
        for (int slot = 0; slot < 2; ++slot) {
            const int fid = tid + slot * 256;           // 0..511 float4s
            const int r = fid >> 4, c4 = (fid & 15) * 4;
            const float4 v = *(const float4*)&kp[headbase + (size_t)(kt0 + r) * HDIM + c4];
            *(float4*)&kt[r][c4] = v;
        }
        __syncthreads();
        float acc = 0.f;
#pragma unroll
        for (int d = 0; d < 64; d += 4) {
            const float4 kv = *(const float4*)&kt[kj][d];
            acc = fmaf(qreg[d], kv.x, acc);
            acc = fmaf(qreg[d + 1], kv.y, acc);
            acc = fmaf(qreg[d + 2], kv.z, acc);
            acc = fmaf(qreg[d + 3], kv.w, acc);
        }
        S[qi][kt0 + kj] = acc * SCALE;
    }
    __syncthreads();

    // ---- phase 2: softmax ----
    {
        const int r = tid >> 5, lane = tid & 31;
        float m = -1e30f;
        for (int c = lane; c < TT; c += 32) m = fmaxf(m, S[r][c]);
#pragma unroll
        for (int off = 16; off > 0; off >>= 1) m = fmaxf(m, __shfl_xor(m, off, 32));
        float s = 0.f;
        for (int c = lane; c < TT; c += 32) {
            const float e = __expf(S[r][c] - m);
            S[r][c] = e;
            s += e;
        }
#pragma unroll
        for (int off = 16; off > 0; off >>= 1) s += __shfl_xor(s, off, 32);
        if (lane == 0) rinv[r] = 1.f / s;
    }
    __syncthreads();

    // normalize in LDS + coalesced write of attn
    {
        const size_t abase = ((((size_t)b * HH + h) << 10) + q0) << 10;
        for (int idx = tid; idx < 8 * 1024; idx += 256) {
            const int r = idx >> 10, c = idx & 1023;
            const float v = S[r][c] * rinv[r];
            S[r][c] = v;
            attn[abase + ((size_t)r << 10) + c] = v;
        }
    }

    // ---- phase 3: ctx = S @ k ----
    const int d  = tid & 63;     // 0..63
    const int qb = tid >> 6;     // 0..3 -> rows qb, qb+4
    float acc3[2] = {0.f, 0.f};
    for (int kt0 = 0; kt0 < TT; kt0 += 32) {
        __syncthreads();
#pragma unroll
        for (int slot = 0; slot < 2; ++slot) {
            const int fid = tid + slot * 256;
            const int r = fid >> 4, c4 = (fid & 15) * 4;
            const float4 v = *(const float4*)&kmat[headbase + (size_t)(kt0 + r) * HDIM + c4];
            *(float4*)&kt[r][c4] = v;
        }
        __syncthreads();
#pragma unroll
        for (int kk = 0; kk < 32; ++kk) {
            const float kv = kt[kk][d];
            acc3[0] = fmaf(S[qb][kt0 + kk], kv, acc3[0]);
            acc3[1] = fmaf(S[qb + 4][kt0 + kk], kv, acc3[1]);
        }
    }
#pragma unroll
    for (int j = 0; j < 2; ++j) {
        const int qr = q0 + qb + 4 * j;
        ctx[((((size_t)b << 10) + qr) * HH + h) * HDIM + d] = acc3[j];
    }
}

extern "C" void kernel_launch(void* const* d_in, const int* in_sizes, int n_in,
                              void* d_out, int out_size, void* d_ws, size_t ws_size,
                              hipStream_t stream)
{
    const float* x  = (const float*)d_in[0];
    const float* pe = (const float*)d_in[1];
    const float* Wc = (const float*)d_in[2];
    const float* bc = (const float*)d_in[3];
    const float* Wp = (const float*)d_in[4];
    const float* bp = (const float*)d_in[5];
    const float* Wo = (const float*)d_in[6];
    const float* bo = (const float*)d_in[7];

    float* out  = (float*)d_out;                       // [B][T][D]   (4M floats)
    float* attn = out + ((size_t)MM << 10);            // [B][H][T][T]

    float* ws    = (float*)d_ws;
    float* qbuf  = ws;                                 // [B][H][T][64]  4M floats
    float* kbuf  = ws + ((size_t)4 << 20);             // [B][H][T][64]
    float* kpbuf = ws + ((size_t)8 << 20);             // pk, then kp=k+pk
    float* ctx   = ws + ((size_t)12 << 20);            // [B][T][D]

    // 1) cqk = x @ Wc^T + bc  -> scatter q, k
    gemm_f32<0><<<dim3(2048 / 128, MM / 128), 256, 0, stream>>>(
        x, Wc, bc, qbuf, kbuf, MM, 2048, DD);
    // 2) pk = pe @ Wp^T + bp  -> scatter pk
    gemm_f32<1><<<dim3(1024 / 128, MM / 128), 256, 0, stream>>>(
        pe, Wp, bp, kpbuf, nullptr, MM, 1024, DD);
    // 3) kp = pk + k
    add_kp_kernel<<<4096, 256, 0, stream>>>(kpbuf, kbuf);
    // 4) fused attention: scores -> softmax -> attn out + ctx
    attn_kernel<<<dim3(TT / 8, HH, BB), 256, 0, stream>>>(
        qbuf, kbuf, kpbuf, attn, ctx);
    // 5) out = ctx @ Wo^T + bo
    gemm_f32<2><<<dim3(1024 / 128, MM / 128), 256, 0, stream>>>(
        ctx, Wo, bo, out, nullptr, MM, 1024, DD);
}

// Round 2
// 613.477 us; speedup vs baseline: 1.9492x; 1.9492x over previous
//
#include <hip/hip_runtime.h>
#include <hip/hip_bf16.h>

// Problem constants (fixed by the reference)
#define BB 4
#define TT 1024
#define DD 1024
#define HH 16
#define HDIM 64
#define MM (BB*TT)          // 4096

typedef unsigned short u16;
typedef __attribute__((ext_vector_type(8))) short bf16x8;   // 8 bf16 = 4 VGPRs
typedef __attribute__((ext_vector_type(4))) float f32x4;

__device__ __forceinline__ u16 f2bf(float f) {
    union { float f; unsigned u; } v; v.f = f;
    return (u16)((v.u + 0x7fffu + ((v.u >> 16) & 1u)) >> 16);   // RNE
}

// ---------------------------------------------------------------------------
// Tiled fp32 GEMM: C[m][n] = sum_k A[m][k] * W[n][k] + bias[n]
// MODE 0: n in [0,2048): c=0 -> q bf16 (pre-scaled by 0.125), c=1 -> k fp32 + k bf16
// MODE 1: pk fp32 scatter [B][H][T][64]
// MODE 2: plain row-major fp32 store
// ---------------------------------------------------------------------------
template<int MODE>
__global__ __launch_bounds__(256)
void gemm_f32(const float* __restrict__ A, const float* __restrict__ W,
              const float* __restrict__ bias,
              float* __restrict__ dstA, u16* __restrict__ dstB, u16* __restrict__ dstC,
              int M, int N, int K)
{
    __shared__ float As[8][132];
    __shared__ float Bs[8][132];

    const int tid = threadIdx.x;
    const int m0 = blockIdx.y * 128;
    const int n0 = blockIdx.x * 128;
    const int tx = tid & 15;
    const int ty = tid >> 4;

    float acc[8][8];
#pragma unroll
    for (int i = 0; i < 8; ++i)
#pragma unroll
        for (int j = 0; j < 8; ++j) acc[i][j] = 0.f;

    const int lr = tid >> 1;
    const int lk = (tid & 1) * 4;

    for (int k0 = 0; k0 < K; k0 += 8) {
        const float4 av = *(const float4*)&A[(size_t)(m0 + lr) * K + k0 + lk];
        const float4 bv = *(const float4*)&W[(size_t)(n0 + lr) * K + k0 + lk];
        __syncthreads();
        As[lk + 0][lr] = av.x; As[lk + 1][lr] = av.y; As[lk + 2][lr] = av.z; As[lk + 3][lr] = av.w;
        Bs[lk + 0][lr] = bv.x; Bs[lk + 1][lr] = bv.y; Bs[lk + 2][lr] = bv.z; Bs[lk + 3][lr] = bv.w;
        __syncthreads();
#pragma unroll
        for (int k = 0; k < 8; ++k) {
            const float4 a0 = *(const float4*)&As[k][ty * 4];
            const float4 a1 = *(const float4*)&As[k][ty * 4 + 64];
            const float4 b0 = *(const float4*)&Bs[k][tx * 4];
            const float4 b1 = *(const float4*)&Bs[k][tx * 4 + 64];
            const float a[8] = {a0.x, a0.y, a0.z, a0.w, a1.x, a1.y, a1.z, a1.w};
            const float b[8] = {b0.x, b0.y, b0.z, b0.w, b1.x, b1.y, b1.z, b1.w};
#pragma unroll
            for (int i = 0; i < 8; ++i)
#pragma unroll
                for (int j = 0; j < 8; ++j)
                    acc[i][j] = fmaf(a[i], b[j], acc[i][j]);
        }
    }

#pragma unroll
    for (int i = 0; i < 8; ++i) {
        const int m = m0 + ty * 4 + (i & 3) + ((i >= 4) ? 64 : 0);
#pragma unroll
        for (int j = 0; j < 8; ++j) {
            const int n = n0 + tx * 4 + (j & 3) + ((j >= 4) ? 64 : 0);
            const float v = acc[i][j] + bias[n];
            if (MODE == 0) {
                const int b = m >> 10, t = m & 1023;
                const int c = n >> 10, hh = (n & 1023) >> 6, d = n & 63;
                const size_t idx = ((((size_t)b * HH + hh) << 10) + t) * HDIM + d;
                if (c == 0) dstB[idx] = f2bf(v * 0.125f);          // q, pre-scaled
                else { dstA[idx] = v; dstC[idx] = f2bf(v); }       // k fp32 + bf16
            } else if (MODE == 1) {
                const int b = m >> 10, t = m & 1023;
                const int hh = n >> 6, d = n & 63;
                dstA[((((size_t)b * HH + hh) << 10) + t) * HDIM + d] = v;
            } else {
                dstA[(size_t)m * N + n] = v;
            }
        }
    }
}

// kp_bf16 = bf16(k_f32 + pk_f32), 4M elements, 8 per thread
__global__ __launch_bounds__(256)
void add_kp_kernel(const float* __restrict__ k, const float* __restrict__ pk,
                   u16* __restrict__ kp)
{
    const size_t i = ((size_t)blockIdx.x * 256 + threadIdx.x) * 8;
    const float4 a0 = *(const float4*)&k[i],  a1 = *(const float4*)&k[i + 4];
    const float4 b0 = *(const float4*)&pk[i], b1 = *(const float4*)&pk[i + 4];
    bf16x8 o;
    o[0] = (short)f2bf(a0.x + b0.x); o[1] = (short)f2bf(a0.y + b0.y);
    o[2] = (short)f2bf(a0.z + b0.z); o[3] = (short)f2bf(a0.w + b0.w);
    o[4] = (short)f2bf(a1.x + b1.x); o[5] = (short)f2bf(a1.y + b1.y);
    o[6] = (short)f2bf(a1.z + b1.z); o[7] = (short)f2bf(a1.w + b1.w);
    *(bf16x8*)&kp[i] = o;
}

// ---------------------------------------------------------------------------
// MFMA attention. Block = one (b,h) x 64 q-rows; 4 waves x 16 rows each.
// Pass 1: rowsums of exp(S) (S in accumulators only).
// Pass 2: recompute S, normalize, write attn, PV via LDS-transposed k.
// A/B frags use identical lane k-mapping (k = 8*(lane>>4)+i) -> layout-robust.
// C/D mapping: col = lane&15, row = 4*(lane>>4)+reg (verified).
// ---------------------------------------------------------------------------
__global__ __launch_bounds__(256)
void attn_mfma(const u16* __restrict__ qg, const u16* __restrict__ kg,
               const u16* __restrict__ kpg,
               float* __restrict__ attn, float* __restrict__ ctx)
{
    __shared__ u16 kp_s[64][72];      // kv-tile of kp, row-major [kk][d]
    __shared__ u16 kT_s[64][72];      // kv-tile of k, transposed [d][kk]
    __shared__ u16 P_s[4][16][72];    // per-wave P tile [q][kk]

    const int tid  = threadIdx.x;
    const int w    = tid >> 6;        // wave 0..3
    const int lane = tid & 63;
    const int lg   = lane >> 4;       // 0..3
    const int lr   = lane & 15;       // 0..15
    const int q0   = blockIdx.x * 64;
    const int h = blockIdx.y, b = blockIdx.z;
    const size_t hb = ((size_t)(b * HH + h)) << 16;    // head base (T*64 elems)

    // Q fragments (rows q0 + w*16 + lr), persistent
    bf16x8 qf0, qf1;
    {
        const size_t base = hb + (size_t)(q0 + w * 16 + lr) * HDIM + lg * 8;
        qf0 = *(const bf16x8*)&qg[base];
        qf1 = *(const bf16x8*)&qg[base + 32];
    }

    const int sr = tid >> 2;          // staging row 0..63
    const int sc = (tid & 3) * 8;     // staging col chunk

    // ---- pass 1: rowsums ----
    float rs[4] = {0.f, 0.f, 0.f, 0.f};
    for (int t = 0; t < TT / 64; ++t) {
        const size_t kvbase = hb + (size_t)(t * 64) * HDIM;
        __syncthreads();
        *(bf16x8*)&kp_s[sr][sc]      = *(const bf16x8*)&kpg[kvbase + sr * HDIM + sc];
        *(bf16x8*)&kp_s[sr][sc + 32] = *(const bf16x8*)&kpg[kvbase + sr * HDIM + sc + 32];
        __syncthreads();
#pragma unroll
        for (int ct = 0; ct < 4; ++ct) {
            f32x4 acc = {0.f, 0.f, 0.f, 0.f};
            const bf16x8 b0 = *(const bf16x8*)&kp_s[ct * 16 + lr][lg * 8];
            const bf16x8 b1 = *(const bf16x8*)&kp_s[ct * 16 + lr][lg * 8 + 32];
            acc = __builtin_amdgcn_mfma_f32_16x16x32_bf16(qf0, b0, acc, 0, 0, 0);
            acc = __builtin_amdgcn_mfma_f32_16x16x32_bf16(qf1, b1, acc, 0, 0, 0);
#pragma unroll
            for (int j = 0; j < 4; ++j) rs[j] += __expf(acc[j]);
        }
    }
#pragma unroll
    for (int off = 1; off < 16; off <<= 1) {
#pragma unroll
        for (int j = 0; j < 4; ++j) rs[j] += __shfl_xor(rs[j], off);
    }
    float ri[4];
#pragma unroll
    for (int j = 0; j < 4; ++j) ri[j] = 1.f / rs[j];

    // ---- pass 2: attn write + PV ----
    f32x4 cacc[4] = {{0,0,0,0},{0,0,0,0},{0,0,0,0},{0,0,0,0}};
    const size_t abase = ((((size_t)b * HH + h) << 10) + q0 + w * 16) << 10;

    for (int t = 0; t < TT / 64; ++t) {
        const size_t kvbase = hb + (size_t)(t * 64) * HDIM;
        __syncthreads();
        *(bf16x8*)&kp_s[sr][sc]      = *(const bf16x8*)&kpg[kvbase + sr * HDIM + sc];
        *(bf16x8*)&kp_s[sr][sc + 32] = *(const bf16x8*)&kpg[kvbase + sr * HDIM + sc + 32];
        {   // stage k transposed: thread owns column d, 8-row groups
            const int d = tid & 63;
#pragma unroll
            for (int rr = (tid >> 6); rr < 8; rr += 4) {
                bf16x8 tv;
#pragma unroll
                for (int j = 0; j < 8; ++j)
                    tv[j] = (short)kg[kvbase + (size_t)(rr * 8 + j) * HDIM + d];
                *(bf16x8*)&kT_s[d][rr * 8] = tv;
            }
        }
        __syncthreads();
#pragma unroll
        for (int ct = 0; ct < 4; ++ct) {
            f32x4 acc = {0.f, 0.f, 0.f, 0.f};
            const bf16x8 b0 = *(const bf16x8*)&kp_s[ct * 16 + lr][lg * 8];
            const bf16x8 b1 = *(const bf16x8*)&kp_s[ct * 16 + lr][lg * 8 + 32];
            acc = __builtin_amdgcn_mfma_f32_16x16x32_bf16(qf0, b0, acc, 0, 0, 0);
            acc = __builtin_amdgcn_mfma_f32_16x16x32_bf16(qf1, b1, acc, 0, 0, 0);
            const int col = t * 64 + ct * 16 + lr;
#pragma unroll
            for (int j = 0; j < 4; ++j) {
                const float p = __expf(acc[j]) * ri[j];
                attn[abase + (size_t)(lg * 4 + j) * TT + col] = p;
                P_s[w][lg * 4 + j][ct * 16 + lr] = f2bf(p);
            }
        }
        asm volatile("s_waitcnt lgkmcnt(0)" ::: "memory");   // P_s write->read, same wave
        const bf16x8 pa0 = *(const bf16x8*)&P_s[w][lr][lg * 8];
        const bf16x8 pa1 = *(const bf16x8*)&P_s[w][lr][lg * 8 + 32];
#pragma unroll
        for (int dt = 0; dt < 4; ++dt) {
            const bf16x8 kb0 = *(const bf16x8*)&kT_s[dt * 16 + lr][lg * 8];
            const bf16x8 kb1 = *(const bf16x8*)&kT_s[dt * 16 + lr][lg * 8 + 32];
            cacc[dt] = __builtin_amdgcn_mfma_f32_16x16x32_bf16(pa0, kb0, cacc[dt], 0, 0, 0);
            cacc[dt] = __builtin_amdgcn_mfma_f32_16x16x32_bf16(pa1, kb1, cacc[dt], 0, 0, 0);
        }
    }

    // ctx [B][T][H*64]
#pragma unroll
    for (int dt = 0; dt < 4; ++dt)
#pragma unroll
        for (int j = 0; j < 4; ++j) {
            const int qr = q0 + w * 16 + lg * 4 + j;
            ctx[(((size_t)b << 10) + qr) * DD + h * HDIM + dt * 16 + lr] = cacc[dt][j];
        }
}

extern "C" void kernel_launch(void* const* d_in, const int* in_sizes, int n_in,
                              void* d_out, int out_size, void* d_ws, size_t ws_size,
                              hipStream_t stream)
{
    const float* x  = (const float*)d_in[0];
    const float* pe = (const float*)d_in[1];
    const float* Wc = (const float*)d_in[2];
    const float* bc = (const float*)d_in[3];
    const float* Wp = (const float*)d_in[4];
    const float* bp = (const float*)d_in[5];
    const float* Wo = (const float*)d_in[6];
    const float* bo = (const float*)d_in[7];

    float* out  = (float*)d_out;                         // [B][T][D]
    float* attn = out + (size_t)MM * DD;                 // [B][H][T][T]

    float* ws    = (float*)d_ws;
    float* kf32  = ws;                                   // [0, 4M)
    float* pkf32 = ws + ((size_t)4 << 20);               // [4M, 8M), reused as ctx
    float* ctx   = pkf32;                                // pk dead after add_kp
    u16*   q16   = (u16*)(ws + ((size_t)8 << 20));       // 4M bf16
    u16*   k16   = (u16*)(ws + ((size_t)10 << 20));
    u16*   kp16  = (u16*)(ws + ((size_t)12 << 20));

    // 1) cqk = x @ Wc^T + bc  -> q bf16 (scaled), k fp32 + bf16
    gemm_f32<0><<<dim3(2048 / 128, MM / 128), 256, 0, stream>>>(
        x, Wc, bc, kf32, q16, k16, MM, 2048, DD);
    // 2) pk = pe @ Wp^T + bp  -> fp32 scatter
    gemm_f32<1><<<dim3(1024 / 128, MM / 128), 256, 0, stream>>>(
        pe, Wp, bp, pkf32, nullptr, nullptr, MM, 1024, DD);
    // 3) kp16 = bf16(k + pk)
    add_kp_kernel<<<2048, 256, 0, stream>>>(kf32, pkf32, kp16);
    // 4) MFMA attention: attn + ctx
    attn_mfma<<<dim3(TT / 64, HH, BB), 256, 0, stream>>>(q16, k16, kp16, attn, ctx);
    // 5) out = ctx @ Wo^T + bo
    gemm_f32<2><<<dim3(1024 / 128, MM / 128), 256, 0, stream>>>(
        ctx, Wo, bo, out, nullptr, nullptr, MM, 1024, DD);
}

// Round 3
// 251.550 us; speedup vs baseline: 4.7536x; 2.4388x over previous
//
#include <hip/hip_runtime.h>
#include <hip/hip_bf16.h>

// Problem constants (fixed by the reference)
#define BB 4
#define TT 1024
#define DD 1024
#define HH 16
#define HDIM 64
#define MM (BB*TT)          // 4096

typedef unsigned short u16;
typedef __attribute__((ext_vector_type(8))) short bf16x8;   // 8 bf16 = 4 VGPRs
typedef __attribute__((ext_vector_type(4))) float f32x4;
typedef __attribute__((ext_vector_type(4))) unsigned short u16x4;

__device__ __forceinline__ u16 f2bf(float f) {
    union { float f; unsigned u; } v; v.f = f;
    return (u16)((v.u + 0x7fffu + ((v.u >> 16) & 1u)) >> 16);   // RNE
}
__device__ __forceinline__ float bf2f(u16 h) {
    union { unsigned u; float f; } v; v.u = ((unsigned)h) << 16; return v.f;
}

// async global->LDS, 16B per lane; lds dest = wave-uniform base + lane*16
__device__ __forceinline__ void gload16(const void* g, void* l) {
    __builtin_amdgcn_global_load_lds(
        (const __attribute__((address_space(1))) unsigned int*)g,
        (__attribute__((address_space(3))) unsigned int*)l, 16, 0, 0);
}

// src f32 -> hi = bf16(src), lo = bf16(src - hi)   (lo may be null)
__global__ __launch_bounds__(256)
void split_kernel(const float* __restrict__ src, u16* __restrict__ hi,
                  u16* __restrict__ lo)
{
    const size_t i = ((size_t)blockIdx.x * 256 + threadIdx.x) * 4;
    const float4 v = *(const float4*)&src[i];
    u16x4 h;
    h[0] = f2bf(v.x); h[1] = f2bf(v.y); h[2] = f2bf(v.z); h[3] = f2bf(v.w);
    *(u16x4*)&hi[i] = h;
    if (lo != nullptr) {
        u16x4 l;
        l[0] = f2bf(v.x - bf2f(h[0]));
        l[1] = f2bf(v.y - bf2f(h[1]));
        l[2] = f2bf(v.z - bf2f(h[2]));
        l[3] = f2bf(v.w - bf2f(h[3]));
        *(u16x4*)&lo[i] = l;
    }
}

// ---------------------------------------------------------------------------
// MFMA GEMM: C = A @ B^T + bias.  A: [M][K] bf16 (hi/lo), B: [N][K] bf16.
// SPLIT: C = Ah.Bh + Al.Bh + Ah.Bl (near-fp32 accuracy).
// 128x128 tile, BK=64, 4 waves (2x2), global_load_lds staging, m97 2-barrier.
// MODE 0 (cqk, N=2048): n<1024 -> q16 = bf16(v*0.125); else kf32 + k16
// MODE 1 (pk):          kp16 = bf16(v + kf32[idx])  (head-scatter layout)
// MODE 2 (out):         dstF row-major f32
// ---------------------------------------------------------------------------
template<bool SPLIT, int MODE>
__global__ __launch_bounds__(256)
void gemm_mfma(const u16* __restrict__ Ah, const u16* __restrict__ Al,
               const u16* __restrict__ Bh, const u16* __restrict__ Bl,
               const float* __restrict__ bias,
               float* __restrict__ dstF, u16* __restrict__ dstH1,
               u16* __restrict__ dstH2, const float* __restrict__ kaux,
               const int M, const int N, const int K)
{
    __shared__ u16 As[128][64];
    __shared__ u16 Bs[128][64];
    __shared__ u16 As2[SPLIT ? 128 : 1][64];
    __shared__ u16 Bs2[SPLIT ? 128 : 1][64];

    const int tid  = threadIdx.x;
    const int w    = tid >> 6;
    const int lane = tid & 63;
    const int lg   = lane >> 4;      // 0..3
    const int lr   = lane & 15;      // 0..15
    const int wr   = w >> 1, wc = w & 1;
    const int m0   = blockIdx.y * 128, n0 = blockIdx.x * 128;

    const f32x4 zero = {0.f, 0.f, 0.f, 0.f};
    f32x4 acc[4][4];
#pragma unroll
    for (int i = 0; i < 4; ++i)
#pragma unroll
        for (int j = 0; j < 4; ++j) acc[i][j] = zero;

    const int srow = tid >> 3;          // 0..31 (row within 32-row issue)
    const int scol = (tid & 7) * 8;     // col chunk
    const int ldr  = w << 3;            // wave-uniform LDS row base

    for (int k0 = 0; k0 < K; k0 += 64) {
        __syncthreads();   // previous tile's reads done
#pragma unroll
        for (int i = 0; i < 4; ++i) {
            const size_t ga = (size_t)(m0 + i * 32 + srow) * K + k0 + scol;
            const size_t gb = (size_t)(n0 + i * 32 + srow) * K + k0 + scol;
            gload16(&Ah[ga], &As[i * 32 + ldr][0]);
            gload16(&Bh[gb], &Bs[i * 32 + ldr][0]);
            if constexpr (SPLIT) {
                gload16(&Al[ga], &As2[i * 32 + ldr][0]);
                gload16(&Bl[gb], &Bs2[i * 32 + ldr][0]);
            }
        }
        __syncthreads();   // staging complete (compiler drains vmcnt)
#pragma unroll
        for (int kk = 0; kk < 2; ++kk) {
            const int koff = kk * 32 + lg * 8;
            bf16x8 a_h[4], b_h[4];
#pragma unroll
            for (int f = 0; f < 4; ++f) {
                a_h[f] = *(const bf16x8*)&As[wr * 64 + f * 16 + lr][koff];
                b_h[f] = *(const bf16x8*)&Bs[wc * 64 + f * 16 + lr][koff];
            }
            if constexpr (SPLIT) {
                bf16x8 a_l[4], b_l[4];
#pragma unroll
                for (int f = 0; f < 4; ++f) {
                    a_l[f] = *(const bf16x8*)&As2[wr * 64 + f * 16 + lr][koff];
                    b_l[f] = *(const bf16x8*)&Bs2[wc * 64 + f * 16 + lr][koff];
                }
#pragma unroll
                for (int mf = 0; mf < 4; ++mf)
#pragma unroll
                    for (int nf = 0; nf < 4; ++nf) {
                        acc[mf][nf] = __builtin_amdgcn_mfma_f32_16x16x32_bf16(a_h[mf], b_h[nf], acc[mf][nf], 0, 0, 0);
                        acc[mf][nf] = __builtin_amdgcn_mfma_f32_16x16x32_bf16(a_l[mf], b_h[nf], acc[mf][nf], 0, 0, 0);
                        acc[mf][nf] = __builtin_amdgcn_mfma_f32_16x16x32_bf16(a_h[mf], b_l[nf], acc[mf][nf], 0, 0, 0);
                    }
            } else {
#pragma unroll
                for (int mf = 0; mf < 4; ++mf)
#pragma unroll
                    for (int nf = 0; nf < 4; ++nf)
                        acc[mf][nf] = __builtin_amdgcn_mfma_f32_16x16x32_bf16(a_h[mf], b_h[nf], acc[mf][nf], 0, 0, 0);
            }
        }
    }

    // epilogue: C/D map col=lane&15, row=4*(lane>>4)+reg (verified)
#pragma unroll
    for (int mf = 0; mf < 4; ++mf)
#pragma unroll
        for (int nf = 0; nf < 4; ++nf)
#pragma unroll
            for (int j = 0; j < 4; ++j) {
                const int gm = m0 + wr * 64 + mf * 16 + lg * 4 + j;
                const int gn = n0 + wc * 64 + nf * 16 + lr;
                const float v = acc[mf][nf][j] + bias[gn];
                if constexpr (MODE == 0) {
                    const int bb = gm >> 10, t = gm & 1023;
                    const int c = gn >> 10, hh = (gn & 1023) >> 6, d = gn & 63;
                    const size_t idx = ((((size_t)bb * HH + hh) << 10) + t) * HDIM + d;
                    if (c == 0) dstH1[idx] = f2bf(v * 0.125f);       // q, pre-scaled
                    else { dstF[idx] = v; dstH2[idx] = f2bf(v); }    // k fp32 + bf16
                } else if constexpr (MODE == 1) {
                    const int bb = gm >> 10, t = gm & 1023;
                    const int hh = gn >> 6, d = gn & 63;
                    const size_t idx = ((((size_t)bb * HH + hh) << 10) + t) * HDIM + d;
                    dstH1[idx] = f2bf(v + kaux[idx]);                // kp = pk + k
                } else {
                    dstF[(size_t)gm * N + gn] = v;
                }
            }
}

// ---------------------------------------------------------------------------
// MFMA attention (unchanged structure from round 2; ctx now emitted as bf16).
// ---------------------------------------------------------------------------
__global__ __launch_bounds__(256)
void attn_mfma(const u16* __restrict__ qg, const u16* __restrict__ kg,
               const u16* __restrict__ kpg,
               float* __restrict__ attn, u16* __restrict__ ch)
{
    __shared__ u16 kp_s[64][72];      // kv-tile of kp, row-major [kk][d]
    __shared__ u16 kT_s[64][72];      // kv-tile of k, transposed [d][kk]
    __shared__ u16 P_s[4][16][72];    // per-wave P tile [q][kk]

    const int tid  = threadIdx.x;
    const int w    = tid >> 6;        // wave 0..3
    const int lane = tid & 63;
    const int lg   = lane >> 4;       // 0..3
    const int lr   = lane & 15;       // 0..15
    const int q0   = blockIdx.x * 64;
    const int h = blockIdx.y, b = blockIdx.z;
    const size_t hb = ((size_t)(b * HH + h)) << 16;    // head base (T*64 elems)

    bf16x8 qf0, qf1;
    {
        const size_t base = hb + (size_t)(q0 + w * 16 + lr) * HDIM + lg * 8;
        qf0 = *(const bf16x8*)&qg[base];
        qf1 = *(const bf16x8*)&qg[base + 32];
    }

    const int sr = tid >> 2;          // staging row 0..63
    const int sc = (tid & 3) * 8;     // staging col chunk

    // ---- pass 1: rowsums ----
    float rs[4] = {0.f, 0.f, 0.f, 0.f};
    for (int t = 0; t < TT / 64; ++t) {
        const size_t kvbase = hb + (size_t)(t * 64) * HDIM;
        __syncthreads();
        *(bf16x8*)&kp_s[sr][sc]      = *(const bf16x8*)&kpg[kvbase + sr * HDIM + sc];
        *(bf16x8*)&kp_s[sr][sc + 32] = *(const bf16x8*)&kpg[kvbase + sr * HDIM + sc + 32];
        __syncthreads();
#pragma unroll
        for (int ct = 0; ct < 4; ++ct) {
            f32x4 acc = {0.f, 0.f, 0.f, 0.f};
            const bf16x8 b0 = *(const bf16x8*)&kp_s[ct * 16 + lr][lg * 8];
            const bf16x8 b1 = *(const bf16x8*)&kp_s[ct * 16 + lr][lg * 8 + 32];
            acc = __builtin_amdgcn_mfma_f32_16x16x32_bf16(qf0, b0, acc, 0, 0, 0);
            acc = __builtin_amdgcn_mfma_f32_16x16x32_bf16(qf1, b1, acc, 0, 0, 0);
#pragma unroll
            for (int j = 0; j < 4; ++j) rs[j] += __expf(acc[j]);
        }
    }
#pragma unroll
    for (int off = 1; off < 16; off <<= 1) {
#pragma unroll
        for (int j = 0; j < 4; ++j) rs[j] += __shfl_xor(rs[j], off);
    }
    float ri[4];
#pragma unroll
    for (int j = 0; j < 4; ++j) ri[j] = 1.f / rs[j];

    // ---- pass 2: attn write + PV ----
    f32x4 cacc[4] = {{0,0,0,0},{0,0,0,0},{0,0,0,0},{0,0,0,0}};
    const size_t abase = ((((size_t)b * HH + h) << 10) + q0 + w * 16) << 10;

    for (int t = 0; t < TT / 64; ++t) {
        const size_t kvbase = hb + (size_t)(t * 64) * HDIM;
        __syncthreads();
        *(bf16x8*)&kp_s[sr][sc]      = *(const bf16x8*)&kpg[kvbase + sr * HDIM + sc];
        *(bf16x8*)&kp_s[sr][sc + 32] = *(const bf16x8*)&kpg[kvbase + sr * HDIM + sc + 32];
        {   // stage k transposed
            const int d = tid & 63;
#pragma unroll
            for (int rr = (tid >> 6); rr < 8; rr += 4) {
                bf16x8 tv;
#pragma unroll
                for (int j = 0; j < 8; ++j)
                    tv[j] = (short)kg[kvbase + (size_t)(rr * 8 + j) * HDIM + d];
                *(bf16x8*)&kT_s[d][rr * 8] = tv;
            }
        }
        __syncthreads();
#pragma unroll
        for (int ct = 0; ct < 4; ++ct) {
            f32x4 acc = {0.f, 0.f, 0.f, 0.f};
            const bf16x8 b0 = *(const bf16x8*)&kp_s[ct * 16 + lr][lg * 8];
            const bf16x8 b1 = *(const bf16x8*)&kp_s[ct * 16 + lr][lg * 8 + 32];
            acc = __builtin_amdgcn_mfma_f32_16x16x32_bf16(qf0, b0, acc, 0, 0, 0);
            acc = __builtin_amdgcn_mfma_f32_16x16x32_bf16(qf1, b1, acc, 0, 0, 0);
            const int col = t * 64 + ct * 16 + lr;
#pragma unroll
            for (int j = 0; j < 4; ++j) {
                const float p = __expf(acc[j]) * ri[j];
                attn[abase + (size_t)(lg * 4 + j) * TT + col] = p;
                P_s[w][lg * 4 + j][ct * 16 + lr] = f2bf(p);
            }
        }
        asm volatile("s_waitcnt lgkmcnt(0)" ::: "memory");   // P_s write->read, same wave
        const bf16x8 pa0 = *(const bf16x8*)&P_s[w][lr][lg * 8];
        const bf16x8 pa1 = *(const bf16x8*)&P_s[w][lr][lg * 8 + 32];
#pragma unroll
        for (int dt = 0; dt < 4; ++dt) {
            const bf16x8 kb0 = *(const bf16x8*)&kT_s[dt * 16 + lr][lg * 8];
            const bf16x8 kb1 = *(const bf16x8*)&kT_s[dt * 16 + lr][lg * 8 + 32];
            cacc[dt] = __builtin_amdgcn_mfma_f32_16x16x32_bf16(pa0, kb0, cacc[dt], 0, 0, 0);
            cacc[dt] = __builtin_amdgcn_mfma_f32_16x16x32_bf16(pa1, kb1, cacc[dt], 0, 0, 0);
        }
    }

    // ctx -> bf16 [B][T][H*64]
#pragma unroll
    for (int dt = 0; dt < 4; ++dt)
#pragma unroll
        for (int j = 0; j < 4; ++j) {
            const int qr = q0 + w * 16 + lg * 4 + j;
            ch[(((size_t)b << 10) + qr) * DD + h * HDIM + dt * 16 + lr] = f2bf(cacc[dt][j]);
        }
}

extern "C" void kernel_launch(void* const* d_in, const int* in_sizes, int n_in,
                              void* d_out, int out_size, void* d_ws, size_t ws_size,
                              hipStream_t stream)
{
    const float* x  = (const float*)d_in[0];
    const float* pe = (const float*)d_in[1];
    const float* Wc = (const float*)d_in[2];
    const float* bc = (const float*)d_in[3];
    const float* Wp = (const float*)d_in[4];
    const float* bp = (const float*)d_in[5];
    const float* Wo = (const float*)d_in[6];
    const float* bo = (const float*)d_in[7];

    float* out  = (float*)d_out;                         // [B][T][D]
    float* attn = out + (size_t)MM * DD;                 // [B][H][T][T]

    // 64 MB workspace layout (in-order stream => safe region reuse)
    char* ws = (char*)d_ws;
    float* kf32 = (float*)(ws);                          // [0,16M)   k fp32
    u16* q16  = (u16*)(ws + ((size_t)16 << 20));         // [16,24M)
    u16* k16  = (u16*)(ws + ((size_t)24 << 20));         // [24,32M)
    u16* kp16 = (u16*)(ws + ((size_t)32 << 20));         // [32,40M)
    // scratch region F = [40M,64M), phase-reused:
    u16* xh  = (u16*)(ws + ((size_t)40 << 20));          // 8MB
    u16* xl  = (u16*)(ws + ((size_t)48 << 20));          // 8MB
    u16* Wch = (u16*)(ws + ((size_t)56 << 20));          // 4MB
    u16* Wcl = (u16*)(ws + ((size_t)60 << 20));          // 4MB
    u16* peh = xh, *pel = xl;                            // after cqk
    u16* Wph = (u16*)(ws + ((size_t)56 << 20));          // 2MB
    u16* Wpl = (u16*)(ws + ((size_t)58 << 20));          // 2MB
    u16* chh = xh;                                       // ctx bf16, after pk
    u16* Woh = (u16*)(ws + ((size_t)48 << 20));          // 2MB

    // 1) splits for cqk
    split_kernel<<<4096, 256, 0, stream>>>(x, xh, xl);
    split_kernel<<<2048, 256, 0, stream>>>(Wc, Wch, Wcl);
    // 2) cqk = x @ Wc^T + bc  (split bf16 ~ fp32) -> q16 (scaled), kf32, k16
    gemm_mfma<true, 0><<<dim3(16, 32), 256, 0, stream>>>(
        xh, xl, Wch, Wcl, bc, kf32, q16, k16, nullptr, MM, 2048, DD);
    // 3) splits for pk
    split_kernel<<<4096, 256, 0, stream>>>(pe, peh, pel);
    split_kernel<<<1024, 256, 0, stream>>>(Wp, Wph, Wpl);
    // 4) pk = pe @ Wp^T + bp; kp16 = bf16(pk + k)
    gemm_mfma<true, 1><<<dim3(8, 32), 256, 0, stream>>>(
        peh, pel, Wph, Wpl, bp, nullptr, kp16, nullptr, kf32, MM, 1024, DD);
    // 5) split Wo (hi only; ctx path is bf16-tolerant)
    split_kernel<<<1024, 256, 0, stream>>>(Wo, Woh, nullptr);
    // 6) attention: attn f32 + ctx bf16
    attn_mfma<<<dim3(TT / 64, HH, BB), 256, 0, stream>>>(q16, k16, kp16, attn, chh);
    // 7) out = ctx @ Wo^T + bo
    gemm_mfma<false, 2><<<dim3(8, 32), 256, 0, stream>>>(
        chh, nullptr, Woh, nullptr, bo, out, nullptr, nullptr, nullptr, MM, 1024, DD);
}